// Round 14
// baseline (456.597 us; speedup 1.0000x reference)
//
#include <hip/hip_runtime.h>
#include <stdint.h>

#define NDRUG 20000
#define NDIS  40000
#define HID   128
#define NE    150000
#define NREL  7
#define RPSTR (NDIS + 1)
#define NS_TOT (NREL * RPSTR)
#define CPX   ((NE + 255) / 256)   // edge-chunks per relation

typedef unsigned short ushort_t;
typedef __attribute__((ext_vector_type(8))) short bf16x8;
typedef __attribute__((ext_vector_type(4))) float f32x4;
typedef const __attribute__((address_space(1))) void gv_t;
typedef __attribute__((address_space(3))) void lv_t;

__device__ __forceinline__ ushort_t f2bf(float f) {
  unsigned u = __float_as_uint(f);
  u += 0x7FFFu + ((u >> 16) & 1u);          // RNE
  return (ushort_t)(u >> 16);
}
__device__ __forceinline__ float bf2f(ushort_t h) {
  return __uint_as_float(((unsigned)h) << 16);
}

// ============ dual-job bf16 MFMA GEMM: C = A[M,K] @ BT[N,K]^T ============
// 128x128 tile, 4 waves, 2-phase prefetch (double-buffered LDS, 1 barrier/step).
struct GemmJob { const ushort_t* A; const ushort_t* BT; const float* bias; void* C; int M, N; };

template<bool BIAS, bool RELU, bool BF16OUT>
__global__ __launch_bounds__(256) void gemm_dual(GemmJob j0, GemmJob j1, int gx0, int K)
{
  __shared__ ushort_t As[2][128 * 32];
  __shared__ ushort_t Bs[2][128 * 32];
  const bool first = blockIdx.x < (unsigned)gx0;
  const GemmJob J = first ? j0 : j1;
  const int bx = first ? blockIdx.x : blockIdx.x - gx0;
  if ((int)blockIdx.y * 128 >= J.N) return;   // uniform exit, before any sync
  const int tid = threadIdx.x;
  const int m0 = bx * 128;
  const int n0 = blockIdx.y * 128;
  const int wave = tid >> 6, lane = tid & 63;
  const int wm = wave & 1, wn = wave >> 1;
  const int l15 = lane & 15, lk = lane >> 4;

  const int rowS = wave * 16 + (lane >> 2);
  const int chunk = (lane & 3) * 8;
  const ushort_t* ga0 = J.A + (size_t)min(m0 + rowS, J.M - 1) * K + chunk;
  const ushort_t* ga1 = J.A + (size_t)min(m0 + rowS + 64, J.M - 1) * K + chunk;
  const ushort_t* gb0 = J.BT + (size_t)(n0 + rowS) * K + chunk;
  const ushort_t* gb1 = J.BT + (size_t)(n0 + rowS + 64) * K + chunk;

#define GEMM_STAGE(buf, koff)                                                              \
  do {                                                                                     \
    __builtin_amdgcn_global_load_lds((gv_t*)(ga0 + (koff)), (lv_t*)(&As[buf][wave * 512]), 16, 0, 0);        \
    __builtin_amdgcn_global_load_lds((gv_t*)(ga1 + (koff)), (lv_t*)(&As[buf][wave * 512 + 2048]), 16, 0, 0); \
    __builtin_amdgcn_global_load_lds((gv_t*)(gb0 + (koff)), (lv_t*)(&Bs[buf][wave * 512]), 16, 0, 0);        \
    __builtin_amdgcn_global_load_lds((gv_t*)(gb1 + (koff)), (lv_t*)(&Bs[buf][wave * 512 + 2048]), 16, 0, 0); \
  } while (0)

  f32x4 acc[4][4] = {};
  const int nt = K >> 5;

  GEMM_STAGE(0, 0);
  __syncthreads();                       // tile 0 landed

  for (int t = 0; t < nt; ++t) {
    if (t + 1 < nt) GEMM_STAGE((t + 1) & 1, (t + 1) * 32);
    const ushort_t* Ab = As[t & 1];
    const ushort_t* Bb = Bs[t & 1];
    bf16x8 af[4], bfg[4];
    #pragma unroll
    for (int m = 0; m < 4; ++m)
      af[m] = *reinterpret_cast<const bf16x8*>(&Ab[(wm * 64 + m * 16 + l15) * 32 + lk * 8]);
    #pragma unroll
    for (int n = 0; n < 4; ++n)
      bfg[n] = *reinterpret_cast<const bf16x8*>(&Bb[(wn * 64 + n * 16 + l15) * 32 + lk * 8]);
    #pragma unroll
    for (int m = 0; m < 4; ++m)
      #pragma unroll
      for (int n = 0; n < 4; ++n)
        acc[m][n] = __builtin_amdgcn_mfma_f32_16x16x32_bf16(af[m], bfg[n], acc[m][n], 0, 0, 0);
    __syncthreads();
  }
#undef GEMM_STAGE

  #pragma unroll
  for (int m = 0; m < 4; ++m) {
    int rbase = m0 + wm * 64 + m * 16 + lk * 4;
    #pragma unroll
    for (int n = 0; n < 4; ++n) {
      int col = n0 + wn * 64 + n * 16 + l15;
      float bv = 0.f;
      if (BIAS) bv = J.bias[col];
      #pragma unroll
      for (int j = 0; j < 4; ++j) {
        int row = rbase + j;
        if (row >= J.M) continue;
        float v = acc[m][n][j] + bv;
        if (RELU) v = fmaxf(v, 0.f);
        if (BF16OUT) ((ushort_t*)J.C)[(size_t)row * J.N + col] = f2bf(v);
        else         ((float*)J.C)[(size_t)row * J.N + col] = v;
      }
    }
  }
}

// ========== fused per-layer weight prep: build_wcat (x2 jobs) + wvec ==========
// blocks [0, wcB): wcat A; [wcB, wcB+wcB2): wcat B; rest: wvec slots.
__global__ __launch_bounds__(256) void prep2(
    const float* __restrict__ W, ushort_t* __restrict__ outA, int ncolA, int4 relsA,
    ushort_t* __restrict__ outB, int ncolB, int4 relsB,
    const float* __restrict__ as_, const float* __restrict__ ad_,
    float* __restrict__ wv, int K, int wcB, int wcB2)
{
  int b = blockIdx.x;
  if (b < wcB + wcB2) {
    const ushort_t* dummy;
    ushort_t* out; int ncol; int4 rels; int id;
    if (b < wcB) { out = outA; ncol = ncolA; rels = relsA; id = b * 256 + threadIdx.x; }
    else         { out = outB; ncol = ncolB; rels = relsB; id = (b - wcB) * 256 + threadIdx.x; }
    (void)dummy;
    if (id >= K * ncol) return;
    int k = id / ncol, c = id - k * ncol;
    int rr = (&rels.x)[c >> 7];
    out[(size_t)c * K + k] = f2bf(W[((size_t)rr * K + k) * HID + (c & 127)]);
    return;
  }
  // wvec part: b2 in [0, 14*(K/4))
  int b2 = b - wcB - wcB2;
  int slot = b2 % 14, kgrp = b2 / 14;
  int r = slot % NREL;
  const float* Wv = (slot < NREL ? W : (const float*)0) ;
  const float* Wm = (slot < NREL ? W : W);   // same tensor for src; dst uses Wdst
  (void)Wv; (void)Wm;
  const float* Wsel = (slot < NREL ? W : ad_ ? W : W);
  (void)Wsel;
  // NOTE: src weights = W (Wsrc); dst weights passed via as_/ad_ pointers below.
  const float* Wd = (const float*)as_;       // as_ repurposed: Wdst pointer
  const float* avs = (const float*)ad_;      // ad_ repurposed: a-vector base (as then ad)
  const float* Wmat = (slot < NREL) ? W : Wd;
  const float* a = avs + slot * HID;
  int wave = threadIdx.x >> 6, lane = threadIdx.x & 63;
  int k = kgrp * 4 + wave;
  if (k >= K) return;
  const float* wr = Wmat + ((size_t)r * K + k) * HID;
  float s = wr[lane] * a[lane] + wr[64 + lane] * a[64 + lane];
  #pragma unroll
  for (int off = 32; off; off >>= 1) s += __shfl_xor(s, off);
  if (lane == 0) wv[slot * 256 + k] = s;
}

// standalone wcat for the final layer
__global__ void build_wcat2(const float* __restrict__ WA, ushort_t* __restrict__ outA,
                            int ncolA, int4 relsA,
                            const float* __restrict__ WB, ushort_t* __restrict__ outB,
                            int ncolB, int4 relsB, int K)
{
  int id = blockIdx.x * 256 + threadIdx.x;
  const float* W; ushort_t* out; int ncol; int4 rels;
  int totA = K * ncolA;
  if (id < totA) { W = WA; out = outA; ncol = ncolA; rels = relsA; }
  else {
    id -= totA;
    if (id >= K * ncolB) return;
    W = WB; out = outB; ncol = ncolB; rels = relsB;
  }
  int k = id / ncol, c = id - k * ncol;
  int rr = (&rels.x)[c >> 7];
  out[(size_t)c * K + k] = f2bf(W[((size_t)rr * K + k) * HID + (c & 127)]);
}

// ================= batched alpha GEMV, both node types in one dispatch =================
struct AlphaJobs { int wslot[8]; int outOff[8]; };

template<int K>
__global__ __launch_bounds__(256) void alpha_dual(
    const ushort_t* __restrict__ XD, const ushort_t* __restrict__ XI,
    const float* __restrict__ wv, float* __restrict__ outBase,
    AlphaJobs jd, AlphaJobs ji, int gbD)
{
  const bool isD = blockIdx.x < (unsigned)gbD;
  const ushort_t* X = isD ? XD : XI;
  const int N = isD ? NDRUG : NDIS;
  const AlphaJobs jobs = isD ? jd : ji;
  int i = (isD ? blockIdx.x : blockIdx.x - gbD) * 256 + threadIdx.x;
  if (i >= N) return;
  float acc[8];
  #pragma unroll
  for (int v = 0; v < 8; ++v) acc[v] = 0.f;
  const ushort_t* xp = X + (size_t)i * K;
  for (int k = 0; k < K; k += 8) {
    uint4 u = *reinterpret_cast<const uint4*>(xp + k);
    unsigned uu[4] = {u.x, u.y, u.z, u.w};
    float xf[8];
    #pragma unroll
    for (int q = 0; q < 4; ++q) {
      xf[2 * q]     = __uint_as_float(uu[q] << 16);
      xf[2 * q + 1] = __uint_as_float(uu[q] & 0xFFFF0000u);
    }
    #pragma unroll
    for (int v = 0; v < 8; ++v) {
      const float* wp = wv + jobs.wslot[v] * 256 + k;
      #pragma unroll
      for (int q = 0; q < 8; ++q) acc[v] += xf[q] * wp[q];
    }
  }
  #pragma unroll
  for (int v = 0; v < 8; ++v) outBase[jobs.outOff[v] + i] = acc[v];
}

// ================= CSR build =================
struct RelIdx { const int* src[NREL]; const int* dst[NREL]; };

// fused cvt + hist: blocks [0, 8*CPX) = XCD-pinned hist (mapping preserved);
// blocks beyond = f32->bf16 convert of both inputs.
__global__ void cvt_hist(RelIdx ri, int* __restrict__ counts,
                         const float* __restrict__ inA, ushort_t* __restrict__ outA, int n8A,
                         const float* __restrict__ inB, ushort_t* __restrict__ outB, int n8B)
{
  int b = blockIdx.x;
  if (b < 8 * CPX) {
    int xcd = b & 7;
    if (xcd >= NREL) return;
    int e = (b >> 3) * 256 + threadIdx.x;
    if (e >= NE) return;
    atomicAdd(&counts[xcd * RPSTR + ri.dst[xcd][e]], 1);
    return;
  }
  int i = (b - 8 * CPX) * 256 + threadIdx.x;
  const float* in; ushort_t* out;
  if (i < n8A) { in = inA; out = outA; }
  else {
    i -= n8A;
    if (i >= n8B) return;
    in = inB; out = outB;
  }
  float4 a = reinterpret_cast<const float4*>(in)[2 * i];
  float4 bq = reinterpret_cast<const float4*>(in)[2 * i + 1];
  ushort_t r[8] = {f2bf(a.x), f2bf(a.y), f2bf(a.z), f2bf(a.w),
                   f2bf(bq.x), f2bf(bq.y), f2bf(bq.z), f2bf(bq.w)};
  reinterpret_cast<uint4*>(out)[i] = *reinterpret_cast<uint4*>(r);
}

__global__ __launch_bounds__(256) void scan_blk(const int* __restrict__ in,
                                                int* __restrict__ partial,
                                                int* __restrict__ bsum, int n)
{
  __shared__ int ts[256];
  int t = threadIdx.x;
  int base = blockIdx.x * 1024 + t * 4;
  int v[4];
  #pragma unroll
  for (int i = 0; i < 4; ++i) v[i] = (base + i < n) ? in[base + i] : 0;
  int s = v[0] + v[1] + v[2] + v[3];
  ts[t] = s; __syncthreads();
  for (int off = 1; off < 256; off <<= 1) {
    int x = (t >= off) ? ts[t - off] : 0;
    __syncthreads();
    ts[t] += x;
    __syncthreads();
  }
  int run = ts[t] - s;
  #pragma unroll
  for (int i = 0; i < 4; ++i) {
    if (base + i < n) partial[base + i] = run;
    run += v[i];
  }
  if (t == 255) bsum[blockIdx.x] = ts[255];
}
__global__ __launch_bounds__(512) void scan_fin(const int* __restrict__ partial,
                                                const int* __restrict__ bsum,
                                                int* __restrict__ rowptr,
                                                int* __restrict__ cursor, int n)
{
  __shared__ int ts[512];
  int t = threadIdx.x;
  ts[t] = (t < (int)blockIdx.x) ? bsum[t] : 0;   // nb <= 512
  __syncthreads();
  #pragma unroll
  for (int off = 256; off; off >>= 1) {
    if (t < off) ts[t] += ts[t + off];
    __syncthreads();
  }
  int base = ts[0];
  #pragma unroll
  for (int i = 0; i < 2; ++i) {
    int idx = blockIdx.x * 1024 + t + i * 512;
    if (idx < n) {
      int v = partial[idx] + base;
      rowptr[idx] = v; cursor[idx] = v;
    }
  }
}
// XCD-pinned scatter (r11: kills partial-line writeback amplification)
__global__ void fill_k(RelIdx ri, int* __restrict__ cursor, int* __restrict__ colsrc) {
  int xcd = blockIdx.x & 7;
  if (xcd >= NREL) return;
  int e = (blockIdx.x >> 3) * 256 + threadIdx.x;
  if (e >= NE) return;
  int d = ri.dst[xcd][e];
  int pos = atomicAdd(&cursor[xcd * RPSTR + d], 1);
  colsrc[pos] = ri.src[xcd][e];
}

// ==== PV gather + fused in-register softmax (r14: tail-split phase B) ====
struct PvRel { int rel; int rowptr_off; int as_off; int ad_off;
               const ushort_t* hs; int hst; int hoff; };
struct PvParams { PvRel dr[3]; PvRel di[4]; };

template<bool RELU>
__global__ __launch_bounds__(256) void pv_multi(
    PvParams P, const int* __restrict__ rowptr, const int* __restrict__ colsrc,
    const float* __restrict__ alphaB, const float* __restrict__ bias,
    ushort_t* __restrict__ outD, ushort_t* __restrict__ outI, int nbD)
{
  const int wave = threadIdx.x >> 6, lane = threadIdx.x & 63;
  const int c0 = 2 * lane;
  const bool isD = blockIdx.x < (unsigned)nbD;
  const int d = (isD ? blockIdx.x : blockIdx.x - nbD) * 4 + wave;
  const int Nd = isD ? NDRUG : NDIS;
  if (d >= Nd) return;        // wave-uniform
  const int nr = isD ? 3 : 4;
  float acc0 = 0.f, acc1 = 0.f;

  // ---- phase A (batched across relations for MLP) ----
  int beg_[4], deg_[4];
  float ad_[4];
  #pragma unroll
  for (int q = 0; q < 4; ++q) {
    deg_[q] = 0; beg_[q] = 0; ad_[q] = 0.f;
    if (q >= nr) continue;
    const PvRel R = isD ? P.dr[q] : P.di[q];
    acc0 += bias[R.rel * HID + c0];
    acc1 += bias[R.rel * HID + c0 + 1];
    beg_[q] = rowptr[R.rowptr_off + d];
    deg_[q] = rowptr[R.rowptr_off + d + 1] - beg_[q];
    ad_[q]  = alphaB[R.ad_off + d];
  }
  int s_[4];
  #pragma unroll
  for (int q = 0; q < 4; ++q)
    s_[q] = (q < nr && deg_[q] <= 64 && lane < deg_[q]) ? colsrc[beg_[q] + lane] : 0;
  float a_[4];
  #pragma unroll
  for (int q = 0; q < 4; ++q) {
    a_[q] = -1e30f;
    if (q < nr && deg_[q] <= 64 && lane < deg_[q]) {
      const PvRel R = isD ? P.dr[q] : P.di[q];
      float t = alphaB[R.as_off + s_[q]] + ad_[q];
      a_[q] = t > 0.f ? t : 0.2f * t;
    }
  }
  float cn_[4];
  #pragma unroll
  for (int q = 0; q < 4; ++q) {
    cn_[q] = 0.f;
    const int dq = deg_[q];
    if (q >= nr || dq == 0 || dq > 64) continue;
    float m = a_[q];
    if (dq <= 16) {
      #pragma unroll
      for (int off = 8; off; off >>= 1) m = fmaxf(m, __shfl_xor(m, off));
    } else {
      #pragma unroll
      for (int off = 32; off; off >>= 1) m = fmaxf(m, __shfl_xor(m, off));
    }
    float ex = (lane < dq) ? __expf(a_[q] - m) : 0.f;
    float sum = ex;
    if (dq <= 16) {
      #pragma unroll
      for (int off = 8; off; off >>= 1) sum += __shfl_xor(sum, off);
    } else {
      #pragma unroll
      for (int off = 32; off; off >>= 1) sum += __shfl_xor(sum, off);
    }
    cn_[q] = ex * (1.f / (sum + 1e-16f));   // 0 in lanes >= dq (and tail lanes)
  }

  // ---- phase B: full 4-edge groups (no bounds checks) + guarded tail ----
  #pragma unroll
  for (int q = 0; q < 4; ++q) {
    if (q >= nr) break;
    const int dq = deg_[q];
    if (dq == 0) continue;
    const PvRel R = isD ? P.dr[q] : P.di[q];
    const ushort_t* hsb = R.hs + R.hoff + c0;
    const int hst = R.hst;

    if (dq <= 64) {
      const int sreg = s_[q];
      const int creg = __float_as_int(cn_[q]);
      const int full = dq & ~3;
      for (int c = 0; c < full; c += 4) {
        float cf[4]; int si[4];
        #pragma unroll
        for (int j = 0; j < 4; ++j) {
          si[j] = __builtin_amdgcn_readlane(sreg, c + j);
          cf[j] = __int_as_float(__builtin_amdgcn_readlane(creg, c + j));
        }
        ushort2 hv[4];
        #pragma unroll
        for (int j = 0; j < 4; ++j)
          hv[j] = *reinterpret_cast<const ushort2*>(hsb + (size_t)si[j] * hst);
        #pragma unroll
        for (int j = 0; j < 4; ++j) {
          acc0 += cf[j] * bf2f(hv[j].x);
          acc1 += cf[j] * bf2f(hv[j].y);
        }
      }
      if (full < dq) {          // 1-3 tail edges; cn=0 in lanes>=dq zeroes them
        float cf[4]; int si[4];
        #pragma unroll
        for (int j = 0; j < 4; ++j) {
          int idx = (full + j) & 63;
          si[j] = __builtin_amdgcn_readlane(sreg, idx);
          cf[j] = (full + j < dq)
                    ? __int_as_float(__builtin_amdgcn_readlane(creg, idx)) : 0.f;
        }
        ushort2 hv[4];
        #pragma unroll
        for (int j = 0; j < 4; ++j)
          hv[j] = *reinterpret_cast<const ushort2*>(hsb + (size_t)si[j] * hst);
        #pragma unroll
        for (int j = 0; j < 4; ++j) {
          acc0 += cf[j] * bf2f(hv[j].x);
          acc1 += cf[j] * bf2f(hv[j].y);
        }
      }
    } else {
      // rare fallback: deg > 64 (3-pass)
      const int beg = beg_[q], end = beg_[q] + dq;
      const float ad = ad_[q];
      const float* as = alphaB + R.as_off;
      float m = -1e30f;
      for (int i = beg + lane; i < end; i += 64) {
        float t = as[colsrc[i]] + ad;
        t = t > 0.f ? t : 0.2f * t;
        m = fmaxf(m, t);
      }
      #pragma unroll
      for (int off = 32; off; off >>= 1) m = fmaxf(m, __shfl_xor(m, off));
      float sum = 0.f;
      for (int i = beg + lane; i < end; i += 64) {
        float t = as[colsrc[i]] + ad;
        t = t > 0.f ? t : 0.2f * t;
        sum += __expf(t - m);
      }
      #pragma unroll
      for (int off = 32; off; off >>= 1) sum += __shfl_xor(sum, off);
      const float inv = 1.f / (sum + 1e-16f);
      for (int cb = beg; cb < end; cb += 64) {
        int n = min(64, end - cb);
        int s = 0; float cn = 0.f;
        if (lane < n) {
          s = colsrc[cb + lane];
          float t = as[s] + ad;
          t = t > 0.f ? t : 0.2f * t;
          cn = __expf(t - m) * inv;
        }
        for (int c = 0; c < n; c += 4) {
          float cf[4]; int si[4];
          #pragma unroll
          for (int j = 0; j < 4; ++j) {
            int idx = (c + j) & 63;
            si[j] = __builtin_amdgcn_readlane(s, idx);
            int cb2 = __builtin_amdgcn_readlane(__float_as_int(cn), idx);
            cf[j] = (c + j < n) ? __int_as_float(cb2) : 0.f;
          }
          ushort2 hv[4];
          #pragma unroll
          for (int j = 0; j < 4; ++j)
            hv[j] = *reinterpret_cast<const ushort2*>(hsb + (size_t)si[j] * hst);
          #pragma unroll
          for (int j = 0; j < 4; ++j) {
            acc0 += cf[j] * bf2f(hv[j].x);
            acc1 += cf[j] * bf2f(hv[j].y);
          }
        }
      }
    }
  }
  if (RELU) { acc0 = fmaxf(acc0, 0.f); acc1 = fmaxf(acc1, 0.f); }
  ushort2 o; o.x = f2bf(acc0); o.y = f2bf(acc1);
  ushort_t* out = isD ? outD : outI;
  *reinterpret_cast<ushort2*>(out + (size_t)d * HID + c0) = o;
}

// ================= host =================
static const int DSTh[NREL] = {1, 0, 1, 0, 1, 1, 0};

struct WsPlan {
  ushort_t *xdb1, *xib1, *xd1b, *xi1b, *xd2b, *xi2b;
  ushort_t *hs_d, *hs_i, *wcatT_d, *wcatT_i, *wfinT_d, *wfinT_i;
  float *alphaB, *wv, *avec;
  int *counts, *rowptr, *cursor, *colsrc, *bsum;
  size_t total_bytes;
};

static WsPlan plan_ws(void* d_ws) {
  WsPlan p;
  ushort_t* s = (ushort_t*)d_ws;
  p.xdb1 = s;     s += (size_t)NDRUG * 256;
  p.xib1 = s;     s += (size_t)NDIS * 256;
  p.xd1b = s;     s += (size_t)NDRUG * HID;
  p.xi1b = s;     s += (size_t)NDIS * HID;
  p.hs_d = s;     s += (size_t)NDRUG * 384;
  p.hs_i = s;     s += (size_t)NDIS * 512;
  p.wcatT_d = s;  s += 384 * 256;
  p.wcatT_i = s;  s += 512 * 256;
  p.wfinT_d = s;  s += 128 * 128;
  p.wfinT_i = s;  s += 128 * 128;
  p.xd2b = p.xdb1;   // alias: xdb1 dead after L1 GEMM/alpha
  p.xi2b = p.xib1;
  float* f = (float*)s;
  p.alphaB = f;   f += (size_t)15 * NDIS;   // 14 rows + 1 dummy
  p.wv = f;       f += 14 * 256;
  p.avec = f;     f += 14 * HID;            // concatenated a_s(7) then a_d(7)
  int* q = (int*)f;
  p.counts = q;   q += NS_TOT;
  p.rowptr = q;   q += NS_TOT;
  p.cursor = q;   q += NS_TOT;
  p.colsrc = q;   q += NREL * NE;
  p.bsum = q;     q += 512;
  p.total_bytes = (size_t)((char*)q - (char*)d_ws);
  return p;
}

// small copy kernel: pack a_s and a_d into one contiguous [14][128] buffer
__global__ void pack_avec(const float* __restrict__ as_, const float* __restrict__ ad_,
                          float* __restrict__ avec)
{
  int i = blockIdx.x * 256 + threadIdx.x;
  if (i < NREL * HID) avec[i] = as_[i];
  else if (i < 14 * HID) avec[i] = ad_[i - NREL * HID];
}

static void run_layer(const ushort_t* XDb, const ushort_t* XIb, int K,
                      const float* Wsrc, const float* Wdst,
                      const float* as_, const float* ad_, const float* bias,
                      ushort_t* outDb, ushort_t* outIb, bool relu,
                      const WsPlan& p, hipStream_t stream)
{
  int4 rd = make_int4(0, 2, 6, 0);
  int4 ri4 = make_int4(1, 3, 4, 5);

  // pack a-vectors, then fused prep (wcat both jobs + wvec)
  pack_avec<<<(14 * HID + 255) / 256, 256, 0, stream>>>(as_, ad_, p.avec);
  int wcB = (K * 384 + 255) / 256, wcB2 = (K * 512 + 255) / 256;
  int wvB = 14 * (K / 4);
  prep2<<<wcB + wcB2 + wvB, 256, 0, stream>>>(
      Wsrc, p.wcatT_d, 384, rd, p.wcatT_i, 512, ri4,
      (const float*)Wdst, (const float*)p.avec, p.wv, K, wcB, wcB2);

  AlphaJobs jd = {};
  jd.wslot[0] = 0;     jd.outOff[0] = 0 * NDIS;
  jd.wslot[1] = 2;     jd.outOff[1] = 2 * NDIS;
  jd.wslot[2] = 6;     jd.outOff[2] = 6 * NDIS;
  jd.wslot[3] = 7 + 1; jd.outOff[3] = (7 + 1) * NDIS;
  jd.wslot[4] = 7 + 3; jd.outOff[4] = (7 + 3) * NDIS;
  jd.wslot[5] = 7 + 6; jd.outOff[5] = (7 + 6) * NDIS;
  jd.wslot[6] = 0;     jd.outOff[6] = 14 * NDIS;   // dummy
  jd.wslot[7] = 0;     jd.outOff[7] = 14 * NDIS;   // dummy
  AlphaJobs ji = {};
  ji.wslot[0] = 1;     ji.outOff[0] = 1 * NDIS;
  ji.wslot[1] = 3;     ji.outOff[1] = 3 * NDIS;
  ji.wslot[2] = 4;     ji.outOff[2] = 4 * NDIS;
  ji.wslot[3] = 5;     ji.outOff[3] = 5 * NDIS;
  ji.wslot[4] = 7 + 0; ji.outOff[4] = (7 + 0) * NDIS;
  ji.wslot[5] = 7 + 2; ji.outOff[5] = (7 + 2) * NDIS;
  ji.wslot[6] = 7 + 4; ji.outOff[6] = (7 + 4) * NDIS;
  ji.wslot[7] = 7 + 5; ji.outOff[7] = (7 + 5) * NDIS;
  int gbD = (NDRUG + 255) / 256, gbI = (NDIS + 255) / 256;
  if (K == 256)
    alpha_dual<256><<<gbD + gbI, 256, 0, stream>>>(XDb, XIb, p.wv, p.alphaB, jd, ji, gbD);
  else
    alpha_dual<128><<<gbD + gbI, 256, 0, stream>>>(XDb, XIb, p.wv, p.alphaB, jd, ji, gbD);

  // hs GEMMs (both node types, one dispatch; 128x128 tiles)
  GemmJob g0 = {XDb, p.wcatT_d, nullptr, p.hs_d, NDRUG, 384};
  GemmJob g1 = {XIb, p.wcatT_i, nullptr, p.hs_i, NDIS, 512};
  int gx0 = (NDRUG + 127) / 128, gx1 = (NDIS + 127) / 128;
  gemm_dual<false, false, true><<<dim3(gx0 + gx1, 4), 256, 0, stream>>>(g0, g1, gx0, K);

  // PV gather with fused softmax
  PvParams P;
  P.dr[0] = {1, 1 * RPSTR, 1 * NDIS, (NREL + 1) * NDIS, p.hs_i, 512, 0};
  P.dr[1] = {3, 3 * RPSTR, 3 * NDIS, (NREL + 3) * NDIS, p.hs_i, 512, 128};
  P.dr[2] = {6, 6 * RPSTR, 6 * NDIS, (NREL + 6) * NDIS, p.hs_d, 384, 256};
  P.di[0] = {0, 0 * RPSTR, 0 * NDIS, (NREL + 0) * NDIS, p.hs_d, 384, 0};
  P.di[1] = {2, 2 * RPSTR, 2 * NDIS, (NREL + 2) * NDIS, p.hs_d, 384, 128};
  P.di[2] = {4, 4 * RPSTR, 4 * NDIS, (NREL + 4) * NDIS, p.hs_i, 512, 256};
  P.di[3] = {5, 5 * RPSTR, 5 * NDIS, (NREL + 5) * NDIS, p.hs_i, 512, 384};
  int nbD = (NDRUG + 3) / 4, nbI = (NDIS + 3) / 4;
  if (relu)
    pv_multi<true><<<nbD + nbI, 256, 0, stream>>>(
        P, p.rowptr, p.colsrc, p.alphaB, bias, outDb, outIb, nbD);
  else
    pv_multi<false><<<nbD + nbI, 256, 0, stream>>>(
        P, p.rowptr, p.colsrc, p.alphaB, bias, outDb, outIb, nbD);
}

extern "C" void kernel_launch(void* const* d_in, const int* in_sizes, int n_in,
                              void* d_out, int out_size, void* d_ws, size_t ws_size,
                              hipStream_t stream) {
  const float* x_drug = (const float*)d_in[0];
  const float* x_dis  = (const float*)d_in[1];
  RelIdx ri;
  for (int r = 0; r < NREL; ++r) {
    const int* e = (const int*)d_in[2 + r];
    ri.src[r] = e; ri.dst[r] = e + NE;
  }
  const float* W1s = (const float*)d_in[9];
  const float* W1d = (const float*)d_in[10];
  const float* a1s = (const float*)d_in[11];
  const float* a1d = (const float*)d_in[12];
  const float* b1  = (const float*)d_in[13];
  const float* W2s = (const float*)d_in[14];
  const float* W2d = (const float*)d_in[15];
  const float* a2s = (const float*)d_in[16];
  const float* a2d = (const float*)d_in[17];
  const float* b2  = (const float*)d_in[18];
  const float* Wdr = (const float*)d_in[19];
  const float* bdr = (const float*)d_in[20];
  const float* Wdi = (const float*)d_in[21];
  const float* bdi = (const float*)d_in[22];

  WsPlan p = plan_ws(d_ws);
  if (p.total_bytes > ws_size) return;

  // CSR build + input cvt, fused first dispatch (hist blocks keep XCD pinning)
  hipMemsetAsync(p.counts, 0, NS_TOT * sizeof(int), stream);
  int n8A = NDRUG * 256 / 8, n8B = NDIS * 256 / 8;
  int cvtB = (n8A + n8B + 255) / 256;
  cvt_hist<<<8 * CPX + cvtB, 256, 0, stream>>>(
      ri, p.counts, x_drug, p.xdb1, n8A, x_dis, p.xib1, n8B);
  int nb = (NS_TOT + 1023) / 1024;
  scan_blk<<<nb, 256, 0, stream>>>(p.counts, p.cursor, p.bsum, NS_TOT);
  scan_fin<<<nb, 512, 0, stream>>>(p.cursor, p.bsum, p.rowptr, p.cursor, NS_TOT);
  fill_k<<<8 * CPX, 256, 0, stream>>>(ri, p.cursor, p.colsrc);

  // Layer 1 (K=256, relu), Layer 2 (K=128)
  run_layer(p.xdb1, p.xib1, 256, W1s, W1d, a1s, a1d, b1, p.xd1b, p.xi1b, true, p, stream);
  run_layer(p.xd1b, p.xi1b, 128, W2s, W2d, a2s, a2d, b2, p.xd2b, p.xi2b, false, p, stream);

  // final linear + bias + relu -> d_out (f32)
  int4 r0 = make_int4(0, 0, 0, 0);
  build_wcat2<<<(128 * 128 * 2 + 255) / 256, 256, 0, stream>>>(
      Wdr, p.wfinT_d, 128, r0, Wdi, p.wfinT_i, 128, r0, 128);
  float* out = (float*)d_out;
  GemmJob f0 = {p.xd2b, p.wfinT_d, bdr, out, NDRUG, 128};
  GemmJob f1 = {p.xi2b, p.wfinT_i, bdi, out + (size_t)NDRUG * HID, NDIS, 128};
  int gx0 = (NDRUG + 127) / 128, gx1 = (NDIS + 127) / 128;
  gemm_dual<true, true, false><<<dim3(gx0 + gx1, 1), 256, 0, stream>>>(f0, f1, gx0, 128);
}

// Round 15
// 425.483 us; speedup vs baseline: 1.0731x; 1.0731x over previous
//
#include <hip/hip_runtime.h>
#include <stdint.h>

#define NDRUG 20000
#define NDIS  40000
#define HID   128
#define NE    150000
#define NREL  7
#define RPSTR (NDIS + 1)
#define NS_TOT (NREL * RPSTR)
#define CPX   ((NE + 255) / 256)   // edge-chunks per relation

typedef unsigned short ushort_t;
typedef __attribute__((ext_vector_type(8))) short bf16x8;
typedef __attribute__((ext_vector_type(4))) float f32x4;
typedef const __attribute__((address_space(1))) void gv_t;
typedef __attribute__((address_space(3))) void lv_t;

__device__ __forceinline__ ushort_t f2bf(float f) {
  unsigned u = __float_as_uint(f);
  u += 0x7FFFu + ((u >> 16) & 1u);          // RNE
  return (ushort_t)(u >> 16);
}
__device__ __forceinline__ float bf2f(ushort_t h) {
  return __uint_as_float(((unsigned)h) << 16);
}

// ============ dual-job bf16 MFMA GEMM: C = A[M,K] @ BT[N,K]^T ============
// 128x128 tile, 4 waves, 2-phase prefetch (double-buffered LDS, 1 barrier/step).
struct GemmJob { const ushort_t* A; const ushort_t* BT; const float* bias; void* C; int M, N; };

template<bool BIAS, bool RELU, bool BF16OUT>
__global__ __launch_bounds__(256) void gemm_dual(GemmJob j0, GemmJob j1, int gx0, int K)
{
  __shared__ ushort_t As[2][128 * 32];
  __shared__ ushort_t Bs[2][128 * 32];
  const bool first = blockIdx.x < (unsigned)gx0;
  const GemmJob J = first ? j0 : j1;
  const int bx = first ? blockIdx.x : blockIdx.x - gx0;
  if ((int)blockIdx.y * 128 >= J.N) return;   // uniform exit, before any sync
  const int tid = threadIdx.x;
  const int m0 = bx * 128;
  const int n0 = blockIdx.y * 128;
  const int wave = tid >> 6, lane = tid & 63;
  const int wm = wave & 1, wn = wave >> 1;
  const int l15 = lane & 15, lk = lane >> 4;

  const int rowS = wave * 16 + (lane >> 2);
  const int chunk = (lane & 3) * 8;
  const ushort_t* ga0 = J.A + (size_t)min(m0 + rowS, J.M - 1) * K + chunk;
  const ushort_t* ga1 = J.A + (size_t)min(m0 + rowS + 64, J.M - 1) * K + chunk;
  const ushort_t* gb0 = J.BT + (size_t)(n0 + rowS) * K + chunk;
  const ushort_t* gb1 = J.BT + (size_t)(n0 + rowS + 64) * K + chunk;

#define GEMM_STAGE(buf, koff)                                                              \
  do {                                                                                     \
    __builtin_amdgcn_global_load_lds((gv_t*)(ga0 + (koff)), (lv_t*)(&As[buf][wave * 512]), 16, 0, 0);        \
    __builtin_amdgcn_global_load_lds((gv_t*)(ga1 + (koff)), (lv_t*)(&As[buf][wave * 512 + 2048]), 16, 0, 0); \
    __builtin_amdgcn_global_load_lds((gv_t*)(gb0 + (koff)), (lv_t*)(&Bs[buf][wave * 512]), 16, 0, 0);        \
    __builtin_amdgcn_global_load_lds((gv_t*)(gb1 + (koff)), (lv_t*)(&Bs[buf][wave * 512 + 2048]), 16, 0, 0); \
  } while (0)

  f32x4 acc[4][4] = {};
  const int nt = K >> 5;

  GEMM_STAGE(0, 0);
  __syncthreads();                       // tile 0 landed

  for (int t = 0; t < nt; ++t) {
    if (t + 1 < nt) GEMM_STAGE((t + 1) & 1, (t + 1) * 32);
    const ushort_t* Ab = As[t & 1];
    const ushort_t* Bb = Bs[t & 1];
    bf16x8 af[4], bfg[4];
    #pragma unroll
    for (int m = 0; m < 4; ++m)
      af[m] = *reinterpret_cast<const bf16x8*>(&Ab[(wm * 64 + m * 16 + l15) * 32 + lk * 8]);
    #pragma unroll
    for (int n = 0; n < 4; ++n)
      bfg[n] = *reinterpret_cast<const bf16x8*>(&Bb[(wn * 64 + n * 16 + l15) * 32 + lk * 8]);
    #pragma unroll
    for (int m = 0; m < 4; ++m)
      #pragma unroll
      for (int n = 0; n < 4; ++n)
        acc[m][n] = __builtin_amdgcn_mfma_f32_16x16x32_bf16(af[m], bfg[n], acc[m][n], 0, 0, 0);
    __syncthreads();
  }
#undef GEMM_STAGE

  #pragma unroll
  for (int m = 0; m < 4; ++m) {
    int rbase = m0 + wm * 64 + m * 16 + lk * 4;
    #pragma unroll
    for (int n = 0; n < 4; ++n) {
      int col = n0 + wn * 64 + n * 16 + l15;
      float bv = 0.f;
      if (BIAS) bv = J.bias[col];
      #pragma unroll
      for (int j = 0; j < 4; ++j) {
        int row = rbase + j;
        if (row >= J.M) continue;
        float v = acc[m][n][j] + bv;
        if (RELU) v = fmaxf(v, 0.f);
        if (BF16OUT) ((ushort_t*)J.C)[(size_t)row * J.N + col] = f2bf(v);
        else         ((float*)J.C)[(size_t)row * J.N + col] = v;
      }
    }
  }
}

// ================= weight prep (two outputs in one dispatch) =================
__global__ void build_wcat2(const float* __restrict__ WA, ushort_t* __restrict__ outA,
                            int ncolA, int4 relsA,
                            const float* __restrict__ WB, ushort_t* __restrict__ outB,
                            int ncolB, int4 relsB, int K)
{
  int id = blockIdx.x * 256 + threadIdx.x;
  const float* W; ushort_t* out; int ncol; int4 rels;
  int totA = K * ncolA;
  if (id < totA) { W = WA; out = outA; ncol = ncolA; rels = relsA; }
  else {
    id -= totA;
    if (id >= K * ncolB) return;
    W = WB; out = outB; ncol = ncolB; rels = relsB;
  }
  int k = id / ncol, c = id - k * ncol;
  int rr = (&rels.x)[c >> 7];
  out[(size_t)c * K + k] = f2bf(W[((size_t)rr * K + k) * HID + (c & 127)]);
}

// wv[slot][k] = sum_j W[r][k][j] * a[r][j]   (slot<7: src, else dst)
__global__ __launch_bounds__(256) void wvec_kernel(
    const float* __restrict__ Wsrc, const float* __restrict__ as_,
    const float* __restrict__ Wdst, const float* __restrict__ ad_,
    float* __restrict__ wv, int K)
{
  int slot = blockIdx.x;
  int r = slot % NREL;
  const float* W = (slot < NREL ? Wsrc : Wdst) + (size_t)r * K * HID;
  const float* a = (slot < NREL ? as_ : ad_) + r * HID;
  int wave = threadIdx.x >> 6, lane = threadIdx.x & 63;
  int k = blockIdx.y * 4 + wave;
  if (k >= K) return;
  float s = W[(size_t)k * HID + lane] * a[lane]
          + W[(size_t)k * HID + 64 + lane] * a[64 + lane];
  #pragma unroll
  for (int off = 32; off; off >>= 1) s += __shfl_xor(s, off);
  if (lane == 0) wv[slot * 256 + k] = s;
}

// ================= f32 -> bf16 convert (two tensors, one dispatch) =================
__global__ void cvt2_f32_bf16(const float* __restrict__ inA, ushort_t* __restrict__ outA, int n8A,
                              const float* __restrict__ inB, ushort_t* __restrict__ outB, int n8B)
{
  int i = blockIdx.x * 256 + threadIdx.x;
  const float* in; ushort_t* out;
  if (i < n8A) { in = inA; out = outA; }
  else {
    i -= n8A;
    if (i >= n8B) return;
    in = inB; out = outB;
  }
  float4 a = reinterpret_cast<const float4*>(in)[2 * i];
  float4 b = reinterpret_cast<const float4*>(in)[2 * i + 1];
  ushort_t r[8] = {f2bf(a.x), f2bf(a.y), f2bf(a.z), f2bf(a.w),
                   f2bf(b.x), f2bf(b.y), f2bf(b.z), f2bf(b.w)};
  reinterpret_cast<uint4*>(out)[i] = *reinterpret_cast<uint4*>(r);
}

// ================= batched alpha GEMV, both node types in one dispatch =================
struct AlphaJobs { int wslot[8]; int outOff[8]; };

template<int K>
__global__ __launch_bounds__(256) void alpha_dual(
    const ushort_t* __restrict__ XD, const ushort_t* __restrict__ XI,
    const float* __restrict__ wv, float* __restrict__ outBase,
    AlphaJobs jd, AlphaJobs ji, int gbD)
{
  const bool isD = blockIdx.x < (unsigned)gbD;
  const ushort_t* X = isD ? XD : XI;
  const int N = isD ? NDRUG : NDIS;
  const AlphaJobs jobs = isD ? jd : ji;
  int i = (isD ? blockIdx.x : blockIdx.x - gbD) * 256 + threadIdx.x;
  if (i >= N) return;
  float acc[8];
  #pragma unroll
  for (int v = 0; v < 8; ++v) acc[v] = 0.f;
  const ushort_t* xp = X + (size_t)i * K;
  for (int k = 0; k < K; k += 8) {
    uint4 u = *reinterpret_cast<const uint4*>(xp + k);
    unsigned uu[4] = {u.x, u.y, u.z, u.w};
    float xf[8];
    #pragma unroll
    for (int q = 0; q < 4; ++q) {
      xf[2 * q]     = __uint_as_float(uu[q] << 16);
      xf[2 * q + 1] = __uint_as_float(uu[q] & 0xFFFF0000u);
    }
    #pragma unroll
    for (int v = 0; v < 8; ++v) {
      const float* wp = wv + jobs.wslot[v] * 256 + k;
      #pragma unroll
      for (int q = 0; q < 8; ++q) acc[v] += xf[q] * wp[q];
    }
  }
  #pragma unroll
  for (int v = 0; v < 8; ++v) outBase[jobs.outOff[v] + i] = acc[v];
}

// ================= CSR build =================
struct RelIdx { const int* src[NREL]; const int* dst[NREL]; };

// XCD-pinned (measured r11: WRITE amplification 56MB -> gone): blockIdx.x & 7
// selects XCD (round-robin dispatch); relation r handled only by XCD r.
__global__ void hist_k(RelIdx ri, int* __restrict__ counts) {
  int xcd = blockIdx.x & 7;
  if (xcd >= NREL) return;
  int e = (blockIdx.x >> 3) * 256 + threadIdx.x;
  if (e >= NE) return;
  atomicAdd(&counts[xcd * RPSTR + ri.dst[xcd][e]], 1);
}
__global__ __launch_bounds__(256) void scan_blk(const int* __restrict__ in,
                                                int* __restrict__ partial,
                                                int* __restrict__ bsum, int n)
{
  __shared__ int ts[256];
  int t = threadIdx.x;
  int base = blockIdx.x * 1024 + t * 4;
  int v[4];
  #pragma unroll
  for (int i = 0; i < 4; ++i) v[i] = (base + i < n) ? in[base + i] : 0;
  int s = v[0] + v[1] + v[2] + v[3];
  ts[t] = s; __syncthreads();
  for (int off = 1; off < 256; off <<= 1) {
    int x = (t >= off) ? ts[t - off] : 0;
    __syncthreads();
    ts[t] += x;
    __syncthreads();
  }
  int run = ts[t] - s;
  #pragma unroll
  for (int i = 0; i < 4; ++i) {
    if (base + i < n) partial[base + i] = run;
    run += v[i];
  }
  if (t == 255) bsum[blockIdx.x] = ts[255];
}
__global__ __launch_bounds__(512) void scan_fin(const int* __restrict__ partial,
                                                const int* __restrict__ bsum,
                                                int* __restrict__ rowptr,
                                                int* __restrict__ cursor, int n)
{
  __shared__ int ts[512];
  int t = threadIdx.x;
  ts[t] = (t < (int)blockIdx.x) ? bsum[t] : 0;   // nb <= 512
  __syncthreads();
  #pragma unroll
  for (int off = 256; off; off >>= 1) {
    if (t < off) ts[t] += ts[t + off];
    __syncthreads();
  }
  int base = ts[0];
  #pragma unroll
  for (int i = 0; i < 2; ++i) {
    int idx = blockIdx.x * 1024 + t + i * 512;
    if (idx < n) {
      int v = partial[idx] + base;
      rowptr[idx] = v; cursor[idx] = v;
    }
  }
}
// XCD-pinned scatter (see hist_k)
__global__ void fill_k(RelIdx ri, int* __restrict__ cursor, int* __restrict__ colsrc) {
  int xcd = blockIdx.x & 7;
  if (xcd >= NREL) return;
  int e = (blockIdx.x >> 3) * 256 + threadIdx.x;
  if (e >= NE) return;
  int d = ri.dst[xcd][e];
  int pos = atomicAdd(&cursor[xcd * RPSTR + d], 1);
  colsrc[pos] = ri.src[xcd][e];
}

// ==== PV gather + fused in-register softmax (r13 measured-best: batched phase A, readlane) ====
struct PvRel { int rel; int rowptr_off; int as_off; int ad_off;
               const ushort_t* hs; int hst; int hoff; };
struct PvParams { PvRel dr[3]; PvRel di[4]; };

template<bool RELU>
__global__ __launch_bounds__(256) void pv_multi(
    PvParams P, const int* __restrict__ rowptr, const int* __restrict__ colsrc,
    const float* __restrict__ alphaB, const float* __restrict__ bias,
    ushort_t* __restrict__ outD, ushort_t* __restrict__ outI, int nbD)
{
  const int wave = threadIdx.x >> 6, lane = threadIdx.x & 63;
  const int c0 = 2 * lane;
  const bool isD = blockIdx.x < (unsigned)nbD;
  const int d = (isD ? blockIdx.x : blockIdx.x - nbD) * 4 + wave;
  const int Nd = isD ? NDRUG : NDIS;
  if (d >= Nd) return;        // wave-uniform (d depends on block+wave only)
  const int nr = isD ? 3 : 4;
  float acc0 = 0.f, acc1 = 0.f;

  // ---- phase A (batched across relations for MLP) ----
  int beg_[4], deg_[4];
  float ad_[4];
  #pragma unroll
  for (int q = 0; q < 4; ++q) {
    deg_[q] = 0; beg_[q] = 0; ad_[q] = 0.f;
    if (q >= nr) continue;
    const PvRel R = isD ? P.dr[q] : P.di[q];
    acc0 += bias[R.rel * HID + c0];
    acc1 += bias[R.rel * HID + c0 + 1];
    beg_[q] = rowptr[R.rowptr_off + d];
    deg_[q] = rowptr[R.rowptr_off + d + 1] - beg_[q];
    ad_[q]  = alphaB[R.ad_off + d];
  }
  int s_[4];                        // 4 independent colsrc gathers in flight
  #pragma unroll
  for (int q = 0; q < 4; ++q)
    s_[q] = (q < nr && deg_[q] <= 64 && lane < deg_[q]) ? colsrc[beg_[q] + lane] : 0;
  float a_[4];                      // 4 independent alpha gathers in flight
  #pragma unroll
  for (int q = 0; q < 4; ++q) {
    a_[q] = -1e30f;
    if (q < nr && deg_[q] <= 64 && lane < deg_[q]) {
      const PvRel R = isD ? P.dr[q] : P.di[q];
      float t = alphaB[R.as_off + s_[q]] + ad_[q];
      a_[q] = t > 0.f ? t : 0.2f * t;
    }
  }
  // softmax reduces (deg<=16: 4-step butterfly over lanes 0-15; else 6-step)
  float cn_[4];
  #pragma unroll
  for (int q = 0; q < 4; ++q) {
    cn_[q] = 0.f;
    const int dq = deg_[q];
    if (q >= nr || dq == 0 || dq > 64) continue;
    float m = a_[q];
    if (dq <= 16) {
      #pragma unroll
      for (int off = 8; off; off >>= 1) m = fmaxf(m, __shfl_xor(m, off));
    } else {
      #pragma unroll
      for (int off = 32; off; off >>= 1) m = fmaxf(m, __shfl_xor(m, off));
    }
    float ex = (lane < dq) ? __expf(a_[q] - m) : 0.f;
    float sum = ex;
    if (dq <= 16) {
      #pragma unroll
      for (int off = 8; off; off >>= 1) sum += __shfl_xor(sum, off);
    } else {
      #pragma unroll
      for (int off = 32; off; off >>= 1) sum += __shfl_xor(sum, off);
    }
    cn_[q] = ex * (1.f / (sum + 1e-16f));   // 0 in lanes >= dq
  }

  // ---- phase B: gather; broadcasts via v_readlane (wave-uniform index) ----
  #pragma unroll
  for (int q = 0; q < 4; ++q) {
    if (q >= nr) break;
    const int dq = deg_[q];
    if (dq == 0) continue;
    const PvRel R = isD ? P.dr[q] : P.di[q];
    const ushort_t* hsb = R.hs + R.hoff + c0;
    const int hst = R.hst;

    if (dq <= 64) {
      const int sreg = s_[q];
      const int creg = __float_as_int(cn_[q]);
      for (int c = 0; c < dq; c += 4) {
        float cf[4]; int si[4];
        #pragma unroll
        for (int j = 0; j < 4; ++j) {
          int idx = c + j;                                   // wave-uniform
          si[j] = __builtin_amdgcn_readlane(sreg, idx & 63);
          int cb = __builtin_amdgcn_readlane(creg, idx & 63);
          cf[j] = (idx < dq) ? __int_as_float(cb) : 0.f;
        }
        ushort2 hv[4];
        #pragma unroll
        for (int j = 0; j < 4; ++j)
          hv[j] = *reinterpret_cast<const ushort2*>(hsb + (size_t)si[j] * hst);
        #pragma unroll
        for (int j = 0; j < 4; ++j) {
          acc0 += cf[j] * bf2f(hv[j].x);
          acc1 += cf[j] * bf2f(hv[j].y);
        }
      }
    } else {
      // rare fallback: deg > 64 (3-pass, readlane broadcasts)
      const int beg = beg_[q], end = beg_[q] + dq;
      const float ad = ad_[q];
      const float* as = alphaB + R.as_off;
      float m = -1e30f;
      for (int i = beg + lane; i < end; i += 64) {
        float t = as[colsrc[i]] + ad;
        t = t > 0.f ? t : 0.2f * t;
        m = fmaxf(m, t);
      }
      #pragma unroll
      for (int off = 32; off; off >>= 1) m = fmaxf(m, __shfl_xor(m, off));
      float sum = 0.f;
      for (int i = beg + lane; i < end; i += 64) {
        float t = as[colsrc[i]] + ad;
        t = t > 0.f ? t : 0.2f * t;
        sum += __expf(t - m);
      }
      #pragma unroll
      for (int off = 32; off; off >>= 1) sum += __shfl_xor(sum, off);
      const float inv = 1.f / (sum + 1e-16f);
      for (int cb = beg; cb < end; cb += 64) {
        int n = min(64, end - cb);
        int s = 0; float cn = 0.f;
        if (lane < n) {
          s = colsrc[cb + lane];
          float t = as[s] + ad;
          t = t > 0.f ? t : 0.2f * t;
          cn = __expf(t - m) * inv;
        }
        for (int c = 0; c < n; c += 4) {
          float cf[4]; int si[4];
          #pragma unroll
          for (int j = 0; j < 4; ++j) {
            int idx = c + j;
            si[j] = __builtin_amdgcn_readlane(s, idx & 63);
            int cb2 = __builtin_amdgcn_readlane(__float_as_int(cn), idx & 63);
            cf[j] = (idx < n) ? __int_as_float(cb2) : 0.f;
          }
          ushort2 hv[4];
          #pragma unroll
          for (int j = 0; j < 4; ++j)
            hv[j] = *reinterpret_cast<const ushort2*>(hsb + (size_t)si[j] * hst);
          #pragma unroll
          for (int j = 0; j < 4; ++j) {
            acc0 += cf[j] * bf2f(hv[j].x);
            acc1 += cf[j] * bf2f(hv[j].y);
          }
        }
      }
    }
  }
  if (RELU) { acc0 = fmaxf(acc0, 0.f); acc1 = fmaxf(acc1, 0.f); }
  ushort2 o; o.x = f2bf(acc0); o.y = f2bf(acc1);
  ushort_t* out = isD ? outD : outI;
  *reinterpret_cast<ushort2*>(out + (size_t)d * HID + c0) = o;
}

// ================= host =================
static const int DSTh[NREL] = {1, 0, 1, 0, 1, 1, 0};

struct WsPlan {
  ushort_t *xdb1, *xib1, *xd1b, *xi1b, *xd2b, *xi2b;
  ushort_t *hs_d, *hs_i, *wcatT_d, *wcatT_i, *wfinT_d, *wfinT_i;
  float *alphaB, *wv;
  int *counts, *rowptr, *cursor, *colsrc, *bsum;
  size_t total_bytes;
};

static WsPlan plan_ws(void* d_ws) {
  WsPlan p;
  ushort_t* s = (ushort_t*)d_ws;
  p.xdb1 = s;     s += (size_t)NDRUG * 256;
  p.xib1 = s;     s += (size_t)NDIS * 256;
  p.xd1b = s;     s += (size_t)NDRUG * HID;
  p.xi1b = s;     s += (size_t)NDIS * HID;
  p.hs_d = s;     s += (size_t)NDRUG * 384;
  p.hs_i = s;     s += (size_t)NDIS * 512;
  p.wcatT_d = s;  s += 384 * 256;
  p.wcatT_i = s;  s += 512 * 256;
  p.wfinT_d = s;  s += 128 * 128;
  p.wfinT_i = s;  s += 128 * 128;
  p.xd2b = p.xdb1;   // alias: xdb1 dead after L1 GEMM/alpha
  p.xi2b = p.xib1;
  float* f = (float*)s;
  p.alphaB = f;   f += (size_t)15 * NDIS;   // 14 rows + 1 dummy
  p.wv = f;       f += 14 * 256;
  int* q = (int*)f;
  p.counts = q;   q += NS_TOT;
  p.rowptr = q;   q += NS_TOT;
  p.cursor = q;   q += NS_TOT;
  p.colsrc = q;   q += NREL * NE;
  p.bsum = q;     q += 512;
  p.total_bytes = (size_t)((char*)q - (char*)d_ws);
  return p;
}

static void run_layer(const ushort_t* XDb, const ushort_t* XIb, int K,
                      const float* Wsrc, const float* Wdst,
                      const float* as_, const float* ad_, const float* bias,
                      ushort_t* outDb, ushort_t* outIb, bool relu,
                      const WsPlan& p, hipStream_t stream)
{
  int4 rd = make_int4(0, 2, 6, 0);
  int4 ri4 = make_int4(1, 3, 4, 5);
  build_wcat2<<<(K * 896 + 255) / 256, 256, 0, stream>>>(
      Wsrc, p.wcatT_d, 384, rd, Wsrc, p.wcatT_i, 512, ri4, K);
  wvec_kernel<<<dim3(14, K / 4), 256, 0, stream>>>(Wsrc, as_, Wdst, ad_, p.wv, K);

  AlphaJobs jd = {};
  jd.wslot[0] = 0;     jd.outOff[0] = 0 * NDIS;
  jd.wslot[1] = 2;     jd.outOff[1] = 2 * NDIS;
  jd.wslot[2] = 6;     jd.outOff[2] = 6 * NDIS;
  jd.wslot[3] = 7 + 1; jd.outOff[3] = (7 + 1) * NDIS;
  jd.wslot[4] = 7 + 3; jd.outOff[4] = (7 + 3) * NDIS;
  jd.wslot[5] = 7 + 6; jd.outOff[5] = (7 + 6) * NDIS;
  jd.wslot[6] = 0;     jd.outOff[6] = 14 * NDIS;   // dummy
  jd.wslot[7] = 0;     jd.outOff[7] = 14 * NDIS;   // dummy
  AlphaJobs ji = {};
  ji.wslot[0] = 1;     ji.outOff[0] = 1 * NDIS;
  ji.wslot[1] = 3;     ji.outOff[1] = 3 * NDIS;
  ji.wslot[2] = 4;     ji.outOff[2] = 4 * NDIS;
  ji.wslot[3] = 5;     ji.outOff[3] = 5 * NDIS;
  ji.wslot[4] = 7 + 0; ji.outOff[4] = (7 + 0) * NDIS;
  ji.wslot[5] = 7 + 2; ji.outOff[5] = (7 + 2) * NDIS;
  ji.wslot[6] = 7 + 4; ji.outOff[6] = (7 + 4) * NDIS;
  ji.wslot[7] = 7 + 5; ji.outOff[7] = (7 + 5) * NDIS;
  int gbD = (NDRUG + 255) / 256, gbI = (NDIS + 255) / 256;
  if (K == 256)
    alpha_dual<256><<<gbD + gbI, 256, 0, stream>>>(XDb, XIb, p.wv, p.alphaB, jd, ji, gbD);
  else
    alpha_dual<128><<<gbD + gbI, 256, 0, stream>>>(XDb, XIb, p.wv, p.alphaB, jd, ji, gbD);

  // hs GEMMs (both node types, one dispatch; 128x128 tiles)
  GemmJob g0 = {XDb, p.wcatT_d, nullptr, p.hs_d, NDRUG, 384};
  GemmJob g1 = {XIb, p.wcatT_i, nullptr, p.hs_i, NDIS, 512};
  int gx0 = (NDRUG + 127) / 128, gx1 = (NDIS + 127) / 128;
  gemm_dual<false, false, true><<<dim3(gx0 + gx1, 4), 256, 0, stream>>>(g0, g1, gx0, K);

  // PV gather with fused softmax
  PvParams P;
  P.dr[0] = {1, 1 * RPSTR, 1 * NDIS, (NREL + 1) * NDIS, p.hs_i, 512, 0};
  P.dr[1] = {3, 3 * RPSTR, 3 * NDIS, (NREL + 3) * NDIS, p.hs_i, 512, 128};
  P.dr[2] = {6, 6 * RPSTR, 6 * NDIS, (NREL + 6) * NDIS, p.hs_d, 384, 256};
  P.di[0] = {0, 0 * RPSTR, 0 * NDIS, (NREL + 0) * NDIS, p.hs_d, 384, 0};
  P.di[1] = {2, 2 * RPSTR, 2 * NDIS, (NREL + 2) * NDIS, p.hs_d, 384, 128};
  P.di[2] = {4, 4 * RPSTR, 4 * NDIS, (NREL + 4) * NDIS, p.hs_i, 512, 256};
  P.di[3] = {5, 5 * RPSTR, 5 * NDIS, (NREL + 5) * NDIS, p.hs_i, 512, 384};
  int nbD = (NDRUG + 3) / 4, nbI = (NDIS + 3) / 4;
  if (relu)
    pv_multi<true><<<nbD + nbI, 256, 0, stream>>>(
        P, p.rowptr, p.colsrc, p.alphaB, bias, outDb, outIb, nbD);
  else
    pv_multi<false><<<nbD + nbI, 256, 0, stream>>>(
        P, p.rowptr, p.colsrc, p.alphaB, bias, outDb, outIb, nbD);
}

extern "C" void kernel_launch(void* const* d_in, const int* in_sizes, int n_in,
                              void* d_out, int out_size, void* d_ws, size_t ws_size,
                              hipStream_t stream) {
  const float* x_drug = (const float*)d_in[0];
  const float* x_dis  = (const float*)d_in[1];
  RelIdx ri;
  for (int r = 0; r < NREL; ++r) {
    const int* e = (const int*)d_in[2 + r];
    ri.src[r] = e; ri.dst[r] = e + NE;
  }
  const float* W1s = (const float*)d_in[9];
  const float* W1d = (const float*)d_in[10];
  const float* a1s = (const float*)d_in[11];
  const float* a1d = (const float*)d_in[12];
  const float* b1  = (const float*)d_in[13];
  const float* W2s = (const float*)d_in[14];
  const float* W2d = (const float*)d_in[15];
  const float* a2s = (const float*)d_in[16];
  const float* a2d = (const float*)d_in[17];
  const float* b2  = (const float*)d_in[18];
  const float* Wdr = (const float*)d_in[19];
  const float* bdr = (const float*)d_in[20];
  const float* Wdi = (const float*)d_in[21];
  const float* bdi = (const float*)d_in[22];

  WsPlan p = plan_ws(d_ws);
  if (p.total_bytes > ws_size) return;

  cvt2_f32_bf16<<<((NDRUG + NDIS) * 256 / 8 + 255) / 256, 256, 0, stream>>>(
      x_drug, p.xdb1, NDRUG * 256 / 8, x_dis, p.xib1, NDIS * 256 / 8);

  // CSR build (reused by both layers); hist/fill XCD-pinned per relation
  hipMemsetAsync(p.counts, 0, NS_TOT * sizeof(int), stream);
  hist_k<<<8 * CPX, 256, 0, stream>>>(ri, p.counts);
  int nb = (NS_TOT + 1023) / 1024;
  scan_blk<<<nb, 256, 0, stream>>>(p.counts, p.cursor, p.bsum, NS_TOT);
  scan_fin<<<nb, 512, 0, stream>>>(p.cursor, p.bsum, p.rowptr, p.cursor, NS_TOT);
  fill_k<<<8 * CPX, 256, 0, stream>>>(ri, p.cursor, p.colsrc);

  // Layer 1 (K=256, relu), Layer 2 (K=128)
  run_layer(p.xdb1, p.xib1, 256, W1s, W1d, a1s, a1d, b1, p.xd1b, p.xi1b, true, p, stream);
  run_layer(p.xd1b, p.xi1b, 128, W2s, W2d, a2s, a2d, b2, p.xd2b, p.xi2b, false, p, stream);

  // final linear + bias + relu -> d_out (f32)
  int4 r0 = make_int4(0, 0, 0, 0);
  build_wcat2<<<(128 * 128 * 2 + 255) / 256, 256, 0, stream>>>(
      Wdr, p.wfinT_d, 128, r0, Wdi, p.wfinT_i, 128, r0, 128);
  float* out = (float*)d_out;
  GemmJob f0 = {p.xd2b, p.wfinT_d, bdr, out, NDRUG, 128};
  GemmJob f1 = {p.xi2b, p.wfinT_i, bdi, out + (size_t)NDRUG * HID, NDIS, 128};
  int gx0 = (NDRUG + 127) / 128, gx1 = (NDIS + 127) / 128;
  gemm_dual<true, true, false><<<dim3(gx0 + gx1, 1), 256, 0, stream>>>(f0, f1, gx0, 128);
}